// Round 3
// baseline (1885.544 us; speedup 1.0000x reference)
//
#include <hip/hip_runtime.h>
#include <cfloat>
#include <math.h>

#define NN 96
#define DIN 16
#define HID 256
#define LAT 128
#define EDGE 4656
#define OUTDIM 6192

// ---- LDS pool offsets (floats) ----
#define XT    0        // 96*97: xT[c][r] = x[r][c]
#define BTo   9312     // 96*96: BT[b][a] = B[a][b]  (16B-aligned rows of 384B)
#define Mo    18528    // 96*97: M[j][a]; doubles as prefix scratch
#define DEGT  27840    // 96
#define DEGR  27936    // 96
#define DRV   28032    // 96
#define GHo   28128    // 256
#define ZSo   28384    // 128
#define H1Do  28512    // 128
#define KLV   28640    // 1 (+3 pad)
#define WFo   28644    // 2*16 norm^2 partials ping-pong
#define REDo  28676    // 64
#define INDSo 28740    // 96 ints
#define CNTo  28836    // 96 ints
#define MSKo  28932    // 96*3 u32
#define NBRo  29220    // u16[96*48] = 2304 floats
#define POOLSZ 31552   // 126,208 B

// prefix scratch inside Mo region
#define T1o   (Mo)         // 1536: t1[96][16]
#define RS1o  (Mo+2048)    // 1024
#define RS2o  (Mo+3072)    // 1024
#define MUo   (Mo+4096)    // 256
#define INVo  (Mo+4352)    // 256
#define KRo   (Mo+4608)    // 128

// ws (global scratch) float offsets
#define WH1   0
#define WX1   24576
#define WT2   49152
#define WH2   73728
#define WOUTP 98304
#define WOUTX 102960

__global__ __launch_bounds__(1024) void k_all(
    const float* __restrict__ feats, const float* __restrict__ adj,
    const float* __restrict__ w1, const float* __restrict__ w2,
    const float* __restrict__ bn1g, const float* __restrict__ bn1b,
    const float* __restrict__ bn2g, const float* __restrict__ bn2b,
    const float* __restrict__ e11w, const float* __restrict__ e11b,
    const float* __restrict__ e12w, const float* __restrict__ e12b,
    const float* __restrict__ d1w, const float* __restrict__ d1b,
    const float* __restrict__ d2w, const float* __restrict__ d2b,
    const float* __restrict__ eps, float* __restrict__ ws,
    float* __restrict__ out) {
  __shared__ __align__(16) float POOL[POOLSZ];
  unsigned* MSK = (unsigned*)&POOL[MSKo];
  int* CNT = (int*)&POOL[CNTo];
  int* INDS = (int*)&POOL[INDSo];
  unsigned short* NBR = (unsigned short*)&POOL[NBRo];
  float* h1ws = ws + WH1;
  float* x1ws = ws + WX1;
  float* t2ws = ws + WT2;
  float* h2ws = ws + WH2;
  float* outpws = ws + WOUTP;
  float* outxws = ws + WOUTX;

  const int t = threadIdx.x;
  const int w = t >> 6, l = t & 63;

  // ---------- ph1: adjacency bitmasks, degt, neighbor lists (j*97 premul) ----------
  if (t < NN) {
    unsigned m0 = 0, m1 = 0, m2 = 0;
    int cnt = 0;
    float dg = 0.f;
    for (int j = 0; j < NN; ++j) {
      float v = adj[t * NN + j];
      if (v > 0.5f) {
        unsigned bit = 1u << (j & 31);
        if (j < 32) m0 |= bit; else if (j < 64) m1 |= bit; else m2 |= bit;
        dg += 1.f;
        if (j != t && cnt < 48) { NBR[t * 48 + cnt] = (unsigned short)(j * 97); ++cnt; }
      }
    }
    MSK[t * 3 + 0] = m0; MSK[t * 3 + 1] = m1; MSK[t * 3 + 2] = m2;
    CNT[t] = cnt;
    POOL[DEGT + t] = dg;
  }
  __syncthreads();

  // ---------- ph2: t1 = adj @ feats (masked sums, incl. diagonal) ----------
  for (int o = t; o < NN * DIN; o += 1024) {
    int i = o >> 4, k = o & 15;
    float s = 0.f;
    for (int wd = 0; wd < 3; ++wd) {
      unsigned mw = MSK[i * 3 + wd];
      while (mw) { int jb = __builtin_ctz(mw); mw &= mw - 1; s += feats[(wd * 32 + jb) * DIN + k]; }
    }
    POOL[T1o + o] = s;
  }
  __syncthreads();

  // ---------- ph3: h1 = t1 @ w1 ----------
  {
    int c = t & 255, q = t >> 8;
    float acc[24];
#pragma unroll
    for (int i = 0; i < 24; ++i) acc[i] = 0.f;
    for (int k = 0; k < DIN; k += 4) {
      float wv0 = w1[k * HID + c], wv1 = w1[(k + 1) * HID + c];
      float wv2 = w1[(k + 2) * HID + c], wv3 = w1[(k + 3) * HID + c];
#pragma unroll
      for (int i = 0; i < 24; ++i) {
        float4 tv = *(const float4*)&POOL[T1o + (q * 24 + i) * DIN + k];
        acc[i] = fmaf(tv.x, wv0, fmaf(tv.y, wv1, fmaf(tv.z, wv2, fmaf(tv.w, wv3, acc[i]))));
      }
    }
#pragma unroll
    for (int i = 0; i < 24; ++i) h1ws[(q * 24 + i) * HID + c] = acc[i];
  }
  __syncthreads();

  // ---------- ph4: bn1 + relu -> x1 ----------
  {
    int c = t & 255, q = t >> 8;
    float s1 = 0.f, s2 = 0.f;
    for (int i = q * 24; i < q * 24 + 24; ++i) { float v = h1ws[i * HID + c]; s1 += v; s2 += v * v; }
    POOL[RS1o + q * 256 + c] = s1; POOL[RS2o + q * 256 + c] = s2;
  }
  __syncthreads();
  if (t < 256) {
    float s1 = POOL[RS1o + t] + POOL[RS1o + 256 + t] + POOL[RS1o + 512 + t] + POOL[RS1o + 768 + t];
    float s2 = POOL[RS2o + t] + POOL[RS2o + 256 + t] + POOL[RS2o + 512 + t] + POOL[RS2o + 768 + t];
    float mu = s1 / 96.f;
    float var = s2 / 96.f - mu * mu;
    POOL[MUo + t] = mu; POOL[INVo + t] = rsqrtf(var + 1e-5f);
  }
  __syncthreads();
  {
    int c = t & 255, q = t >> 8;
    float mu = POOL[MUo + c], iv = POOL[INVo + c], g = bn1g[c], b = bn1b[c];
    for (int i = q * 24; i < q * 24 + 24; ++i) {
      float v = h1ws[i * HID + c];
      x1ws[i * HID + c] = fmaxf((v - mu) * iv * g + b, 0.f);
    }
  }
  __syncthreads();

  // ---------- ph5: t2 = adj @ x1 (masked sums) ----------
  for (int o = t; o < NN * HID; o += 1024) {
    int i = o >> 8, c = o & 255;
    float s = 0.f;
    for (int wd = 0; wd < 3; ++wd) {
      unsigned mw = MSK[i * 3 + wd];
      while (mw) { int jb = __builtin_ctz(mw); mw &= mw - 1; s += x1ws[(wd * 32 + jb) * HID + c]; }
    }
    t2ws[o] = s;
  }
  __syncthreads();

  // ---------- ph6: h2 = t2 @ w2 ----------
  {
    int c = t & 255, q = t >> 8;
    float acc[24];
#pragma unroll
    for (int i = 0; i < 24; ++i) acc[i] = 0.f;
    for (int k = 0; k < HID; k += 4) {
      float wv0 = w2[k * HID + c], wv1 = w2[(k + 1) * HID + c];
      float wv2 = w2[(k + 2) * HID + c], wv3 = w2[(k + 3) * HID + c];
#pragma unroll
      for (int i = 0; i < 24; ++i) {
        float4 tv = *(const float4*)&t2ws[(q * 24 + i) * HID + k];
        acc[i] = fmaf(tv.x, wv0, fmaf(tv.y, wv1, fmaf(tv.z, wv2, fmaf(tv.w, wv3, acc[i]))));
      }
    }
#pragma unroll
    for (int i = 0; i < 24; ++i) h2ws[(q * 24 + i) * HID + c] = acc[i];
  }
  __syncthreads();

  // ---------- ph7: bn2 stats + gh (column sums of bn2 output) ----------
  {
    int c = t & 255, q = t >> 8;
    float s1 = 0.f, s2 = 0.f;
    for (int i = q * 24; i < q * 24 + 24; ++i) { float v = h2ws[i * HID + c]; s1 += v; s2 += v * v; }
    POOL[RS1o + q * 256 + c] = s1; POOL[RS2o + q * 256 + c] = s2;
  }
  __syncthreads();
  if (t < 256) {
    float s1 = POOL[RS1o + t] + POOL[RS1o + 256 + t] + POOL[RS1o + 512 + t] + POOL[RS1o + 768 + t];
    float s2 = POOL[RS2o + t] + POOL[RS2o + 256 + t] + POOL[RS2o + 512 + t] + POOL[RS2o + 768 + t];
    float mu = s1 / 96.f;
    float var = s2 / 96.f - mu * mu;
    POOL[MUo + t] = mu; POOL[INVo + t] = rsqrtf(var + 1e-5f);
  }
  __syncthreads();
  {
    int c = t & 255, q = t >> 8;
    float mu = POOL[MUo + c], iv = POOL[INVo + c], g = bn2g[c], b = bn2b[c];
    float s = 0.f;
    for (int i = q * 24; i < q * 24 + 24; ++i) {
      float v = h2ws[i * HID + c];
      s += (v - mu) * iv * g + b;
    }
    POOL[RS1o + q * 256 + c] = s;
  }
  __syncthreads();
  if (t < 256)
    POOL[GHo + t] = POOL[RS1o + t] + POOL[RS1o + 256 + t] + POOL[RS1o + 512 + t] + POOL[RS1o + 768 + t];
  __syncthreads();

  // ---------- ph8: VAE heads + z + kl ----------
  if (t < LAT) {
    float a = e11b[t], cc = e12b[t];
    for (int k = 0; k < HID; ++k) {
      float g = POOL[GHo + k];
      a = fmaf(e11w[t * HID + k], g, a);
      cc = fmaf(e12w[t * HID + k], g, cc);
    }
    POOL[ZSo + t] = eps[t] * expf(0.5f * cc) + a;
    POOL[KRo + t] = 1.f + cc - a * a - expf(cc);
  }
  __syncthreads();
  if (t == 0) {
    float s = 0.f;
    for (int k = 0; k < 128; ++k) s += POOL[KRo + k];
    POOL[KLV] = -0.5f * s / (96.f * 96.f);
  }
  __syncthreads();
  // ---------- ph9: h1d = relu(d1w @ z + d1b) ----------
  if (t < LAT) {
    float hv = d1b[t];
    for (int k = 0; k < LAT; ++k) hv = fmaf(d1w[t * LAT + k], POOL[ZSo + k], hv);
    POOL[H1Do + t] = fmaxf(hv, 0.f);
  }
  __syncthreads();

  // ---------- ph10: decoder ----------
  for (int o = t; o < OUTDIM; o += 1024) {
    const float4* wr = (const float4*)(d2w + o * LAT);
    float s = d2b[o];
    for (int k4 = 0; k4 < 32; ++k4) {
      float4 v = wr[k4];
      const float* hz = &POOL[H1Do + k4 * 4];
      s = fmaf(v.x, hz[0], fmaf(v.y, hz[1], fmaf(v.z, hz[2], fmaf(v.w, hz[3], s))));
    }
    if (o < EDGE) outpws[o] = 1.f / (1.f + expf(-s));
    else outxws[o - EDGE] = s;
  }
  __syncthreads();

  // ---------- ph11: degr, dr ----------
  if (t < NN) {
    float s = 0.f;
    for (int b = 0; b < NN; ++b) {
      int i2 = min(t, b), j2 = max(t, b);
      int e = i2 * NN - (i2 * (i2 - 1)) / 2 + (j2 - i2);
      s += outpws[e];
    }
    POOL[DEGR + t] = s;
    int ed = t * NN - (t * (t - 1)) / 2;
    POOL[DRV + t] = outpws[ed];
  }
  __syncthreads();

  // ---------- ph12: BT build + xT init ----------
  for (int o = t; o < NN * NN; o += 1024) {
    int b = o / NN, a = o - b * NN;
    float v = 0.f;
    if (a != b) {
      int i2 = min(a, b), j2 = max(a, b);
      int e = i2 * NN - (i2 * (i2 - 1)) / 2 + (j2 - i2);
      v = outpws[e] * POOL[DRV + a] * POOL[DRV + b];
    }
    POOL[BTo + o] = v;   // BT[b][a] = B[a][b]
  }
  for (int o = t; o < 9312; o += 1024) POOL[XT + o] = 1.f / 96.f;
  __syncthreads();

  // ---------- MPM: 50 iterations, all in LDS ----------
  for (int m = 0; m < 50; ++m) {
    // max phase: M[j][a] = max_b B[a][b]*x[j][b]
    if (w < 12) {
      int jj, a0;
      if (w < 8) { jj = l; a0 = 12 * w; }
      else { jj = 64 + (l & 31); a0 = 12 * ((w - 8) * 2 + (l >> 5)); }
      float mx[12];
#pragma unroll
      for (int k = 0; k < 12; ++k) mx[k] = 0.f;
#pragma unroll 2
      for (int b2 = 0; b2 < 48; ++b2) {
        int b = b2 * 2;
        float xv0 = POOL[XT + b * 97 + jj];
        float xv1 = POOL[XT + (b + 1) * 97 + jj];
        float4 B00 = *(const float4*)&POOL[BTo + b * 96 + a0];
        float4 B01 = *(const float4*)&POOL[BTo + b * 96 + a0 + 4];
        float4 B02 = *(const float4*)&POOL[BTo + b * 96 + a0 + 8];
        float4 B10 = *(const float4*)&POOL[BTo + (b + 1) * 96 + a0];
        float4 B11 = *(const float4*)&POOL[BTo + (b + 1) * 96 + a0 + 4];
        float4 B12 = *(const float4*)&POOL[BTo + (b + 1) * 96 + a0 + 8];
        mx[0] = fmaxf(fmaxf(mx[0], B00.x * xv0), B10.x * xv1);
        mx[1] = fmaxf(fmaxf(mx[1], B00.y * xv0), B10.y * xv1);
        mx[2] = fmaxf(fmaxf(mx[2], B00.z * xv0), B10.z * xv1);
        mx[3] = fmaxf(fmaxf(mx[3], B00.w * xv0), B10.w * xv1);
        mx[4] = fmaxf(fmaxf(mx[4], B01.x * xv0), B11.x * xv1);
        mx[5] = fmaxf(fmaxf(mx[5], B01.y * xv0), B11.y * xv1);
        mx[6] = fmaxf(fmaxf(mx[6], B01.z * xv0), B11.z * xv1);
        mx[7] = fmaxf(fmaxf(mx[7], B01.w * xv0), B11.w * xv1);
        mx[8] = fmaxf(fmaxf(mx[8], B02.x * xv0), B12.x * xv1);
        mx[9] = fmaxf(fmaxf(mx[9], B02.y * xv0), B12.y * xv1);
        mx[10] = fmaxf(fmaxf(mx[10], B02.z * xv0), B12.z * xv1);
        mx[11] = fmaxf(fmaxf(mx[11], B02.w * xv0), B12.w * xv1);
      }
#pragma unroll
      for (int k = 0; k < 12; ++k) POOL[Mo + jj * 97 + a0 + k] = mx[k];
    }
    __syncthreads();

    // sum phase: xn[i][a] = (x[i][a]*Sd(i,a) + sum_{j in N(i)\i} M[j][a]) * inv
    float inv = 1.f;
    if (m > 0) {
      int pp = (m & 1) ^ 1;
      float sv = 0.f;
#pragma unroll
      for (int q = 0; q < 16; ++q) sv += POOL[WFo + pp * 16 + q];
      inv = rsqrtf(sv);
    }
    float ss = 0.f;
    {
      bool sact; int aa, i0;
      if (w < 8) { sact = true; aa = l; i0 = 12 * w; }
      else { sact = (l < 32); aa = 64 + (l & 31); i0 = 12 * (w - 8); }
      if (sact) {
        float drA = POOL[DRV + aa], dgrA = POOL[DEGR + aa];
        for (int q = 0; q < 12; ++q) {
          int i = i0 + q;
          float macc = 0.f;
          int cnt = CNT[i];
          for (int e2 = 0; e2 < cnt; ++e2) {
            int j97 = NBR[i * 48 + e2];
            macc += POOL[Mo + j97 + aa];
          }
          float xv = POOL[XT + aa * 97 + i];
          float sd = drA / (fabsf(POOL[DEGT + i] - dgrA) + 1.f);
          float v = (xv * sd + macc) * inv;
          POOL[XT + aa * 97 + i] = v;
          ss += v * v;
        }
      }
    }
#pragma unroll
    for (int off = 32; off >= 1; off >>= 1) ss += __shfl_xor(ss, off);
    if (l == 0) POOL[WFo + (m & 1) * 16 + w] = ss;
    __syncthreads();
  }

  // ---------- greedy assignment (wave 0; incremental row-max, exact first-index tie-break) ----------
  if (w == 0) {
    float mA = -1.f, mB = -1.f; int aA = 0, aB = 0;
    bool alA = true, alB = (l < 32);
    for (int c = 0; c < NN; ++c) { float v = POOL[XT + c * 97 + l]; if (v > mA) { mA = v; aA = c; } }
    if (l < 32) for (int c = 0; c < NN; ++c) { float v = POOL[XT + c * 97 + 64 + l]; if (v > mB) { mB = v; aB = c; } }
    unsigned long long colm0 = ~0ull;
    unsigned long long colm1 = 0xFFFFFFFFull;
    for (int step = 0; step < NN; ++step) {
      unsigned long long kA = alA
        ? ((((unsigned long long)__float_as_uint(mA)) << 32) | (unsigned)(0x3FFF - (l * NN + aA))) : 0ull;
      unsigned long long kB = alB
        ? ((((unsigned long long)__float_as_uint(mB)) << 32) | (unsigned)(0x3FFF - ((64 + l) * NN + aB))) : 0ull;
      unsigned long long kk = kA > kB ? kA : kB;
#pragma unroll
      for (int off = 1; off < 64; off <<= 1) {
        unsigned long long o = __shfl_xor(kk, off);
        if (o > kk) kk = o;
      }
      int flat = 0x3FFF - (int)(kk & 0xFFFFFFFFull);
      int r = flat / NN, c = flat - (flat / NN) * NN;
      if (l == 0) INDS[c] = r;
      if (c < 64) colm0 &= ~(1ull << c); else colm1 &= ~(1ull << (c - 64));
      if (l == r) alA = false;
      if (alB && (64 + l) == r) alB = false;
      if (alA && aA == c) {
        mA = -1.f; aA = 0;
        unsigned long long mm0 = colm0;
        while (mm0) { int c2 = __builtin_ctzll(mm0); mm0 &= mm0 - 1; float v = POOL[XT + c2 * 97 + l]; if (v > mA) { mA = v; aA = c2; } }
        unsigned long long mm1 = colm1;
        while (mm1) { int c2 = 64 + __builtin_ctzll(mm1); mm1 &= mm1 - 1; float v = POOL[XT + c2 * 97 + l]; if (v > mA) { mA = v; aA = c2; } }
      }
      if (alB && aB == c) {
        mB = -1.f; aB = 0;
        unsigned long long mm0 = colm0;
        while (mm0) { int c2 = __builtin_ctzll(mm0); mm0 &= mm0 - 1; float v = POOL[XT + c2 * 97 + 64 + l]; if (v > mB) { mB = v; aB = c2; } }
        unsigned long long mm1 = colm1;
        while (mm1) { int c2 = 64 + __builtin_ctzll(mm1); mm1 &= mm1 - 1; float v = POOL[XT + c2 * 97 + 64 + l]; if (v > mB) { mB = v; aB = c2; } }
      }
    }
  }
  __syncthreads();

  // ---------- losses ----------
  float accf = 0.f;
  for (int p = t; p < NN * DIN; p += 1024) {
    int i = p >> 4, k = p & 15;
    float d = outxws[p] - feats[INDS[i] * DIN + k];
    accf += d * d;
  }
  float accb = 0.f;
  for (int e = t; e < EDGE; e += 1024) {
    int i = (int)((193.0f - sqrtf(193.0f * 193.0f - 8.0f * (float)e)) * 0.5f);
    if (i < 0) i = 0; if (i > 95) i = 95;
    while (i < 95 && (i + 1) * NN - ((i + 1) * i) / 2 <= e) ++i;
    while (i > 0 && i * NN - (i * (i - 1)) / 2 > e) --i;
    int j = i + (e - (i * NN - (i * (i - 1)) / 2));
    int ri = INDS[i], rj = INDS[j];
    float tv = (float)((MSK[ri * 3 + (rj >> 5)] >> (rj & 31)) & 1u);
    float pr = outpws[e];
    float l1 = fmaxf(logf(pr), -100.f);
    float l0 = fmaxf(log1pf(-pr), -100.f);
    accb += tv * l1 + (1.f - tv) * l0;
  }
#pragma unroll
  for (int off = 32; off >= 1; off >>= 1) { accf += __shfl_xor(accf, off); accb += __shfl_xor(accb, off); }
  if (l == 0) { POOL[REDo + w] = accf; POOL[REDo + 16 + w] = accb; }
  __syncthreads();
  if (t == 0) {
    float ff = 0.f, bb = 0.f;
    for (int q2 = 0; q2 < 16; ++q2) { ff += POOL[REDo + q2]; bb += POOL[REDo + 16 + q2]; }
    out[0] = (-bb / (float)EDGE) + POOL[KLV] + ff / (float)(NN * DIN);
  }
}

extern "C" void kernel_launch(void* const* d_in, const int* in_sizes, int n_in,
                              void* d_out, int out_size, void* d_ws, size_t ws_size,
                              hipStream_t stream) {
  const float* feats = (const float*)d_in[0];
  const float* adj   = (const float*)d_in[1];
  const float* w1    = (const float*)d_in[2];
  const float* w2    = (const float*)d_in[3];
  const float* bn1g  = (const float*)d_in[4];
  const float* bn1b  = (const float*)d_in[5];
  const float* bn2g  = (const float*)d_in[6];
  const float* bn2b  = (const float*)d_in[7];
  const float* e11w  = (const float*)d_in[8];
  const float* e11b  = (const float*)d_in[9];
  const float* e12w  = (const float*)d_in[10];
  const float* e12b  = (const float*)d_in[11];
  const float* d1w   = (const float*)d_in[12];
  const float* d1b   = (const float*)d_in[13];
  const float* d2w   = (const float*)d_in[14];
  const float* d2b   = (const float*)d_in[15];
  const float* eps   = (const float*)d_in[16];

  k_all<<<1, 1024, 0, stream>>>(feats, adj, w1, w2, bn1g, bn1b, bn2g, bn2b,
                                e11w, e11b, e12w, e12b, d1w, d1b, d2w, d2b,
                                eps, (float*)d_ws, (float*)d_out);
}